// Round 6
// baseline (49.418 us; speedup 1.0000x reference)
//
#include <hip/hip_runtime.h>
#include <math.h>

#define C_IN 80
#define L_IN 3000
#define OUT_C 512
#define TL1 128      // K1: l positions per block
#define NT1 256
#define NT2 256
#define TL2 256      // K2: l positions per block
#define OH  256      // K2: o rows per block

struct c2f { float x, y; };

__device__ __forceinline__ c2f cmul(c2f a, c2f b) {
    return { a.x*b.x - a.y*b.y, a.x*b.y + a.y*b.x };
}
__device__ __forceinline__ c2f csel(c2f a, c2f b, int bit) {
    c2f r; r.x = bit ? b.x : a.x; r.y = bit ? b.y : a.y; return r;
}
__device__ __forceinline__ float quadform(const float4* __restrict__ A, float4 p) {
    float4 r0 = A[0], r1 = A[1], r2 = A[2], r3 = A[3];
    return p.x*(r0.x*p.x + r0.y*p.y + r0.z*p.z + r0.w*p.w)
         + p.y*(r1.x*p.x + r1.y*p.y + r1.z*p.z + r1.w*p.w)
         + p.z*(r2.x*p.x + r2.y*p.y + r2.z*p.z + r2.w*p.w)
         + p.w*(r3.x*p.x + r3.y*p.y + r3.z*p.z + r3.w*p.w);
}

// ---------- K1: conv + quantum quadratic forms -> expz[b][l] (float4) ----------
__global__ __launch_bounds__(NT1) void qconv_expz_kernel(
    const float* __restrict__ x,
    const float* __restrict__ W_pre,
    const float* __restrict__ b_pre,
    const float* __restrict__ qw,
    float4* __restrict__ expz)
{
    __shared__ float4 s_wpre[C_IN*3];
    __shared__ float4 s_A[4][4];
    __shared__ float4 s_part[TL1];

    const int t  = threadIdx.x;
    const int b  = blockIdx.y;
    const int l0 = blockIdx.x * TL1;

    for (int i = t; i < C_IN*3; i += NT1) {
        s_wpre[i] = make_float4(W_pre[0*C_IN*3 + i], W_pre[1*C_IN*3 + i],
                                W_pre[2*C_IN*3 + i], W_pre[3*C_IN*3 + i]);
    }
    __syncthreads();

    if (t < 64) {
        c2f U[4][2][2];
        #pragma unroll
        for (int i = 0; i < 4; ++i) {
            float phi = qw[i*3+0], theta = qw[i*3+1], omega = qw[i*3+2];
            float sh, ch;  sincosf(0.5f*theta, &sh, &ch);
            float s1, c1;  sincosf(0.5f*(phi+omega), &s1, &c1);
            float s2, cv;  sincosf(0.5f*(phi-omega), &s2, &cv);
            U[i][0][0] = {  c1*ch, -s1*ch };
            U[i][0][1] = { -cv*sh, -s2*sh };
            U[i][1][0] = {  cv*sh, -s2*sh };
            U[i][1][1] = {  c1*ch,  s1*ch };
        }
        const int q  = t >> 4;
        const int j  = (t >> 2) & 3;
        const int jp = t & 3;
        const int j2  = (j  >> 1) & 1, j3  = j  & 1;
        const int jp2 = (jp >> 1) & 1, jp3 = jp & 1;
        float s = 0.f;
        #pragma unroll
        for (int k = 0; k < 16; ++k) {
            int m = k ^ ((k >> 1) & 1);
            m ^= ((m >> 2) & 1) << 1;
            m ^= ((m >> 3) & 1) << 2;
            const int m0 = (m >> 3) & 1, m1 = (m >> 2) & 1;
            const int m2 = (m >> 1) & 1, m3 = m & 1;
            c2f w01 = cmul(U[0][m0][0], U[1][m1][0]);
            c2f av = cmul(w01, cmul(csel(U[2][m2][0], U[2][m2][1], j2),
                                    csel(U[3][m3][0], U[3][m3][1], j3)));
            c2f bv = cmul(w01, cmul(csel(U[2][m2][0], U[2][m2][1], jp2),
                                    csel(U[3][m3][0], U[3][m3][1], jp3)));
            float z = 1.f - 2.f * ((k >> (3 - q)) & 1);
            s += z * (av.x*bv.x + av.y*bv.y);
        }
        ((float*)s_A)[t] = s;
    }

    const int i = t & (TL1 - 1);
    const int h = t >> 7;
    const int l = l0 + i;
    const bool lvalid = (l < L_IN);

    float4 acc = (h == 0) ? make_float4(b_pre[0], b_pre[1], b_pre[2], b_pre[3])
                          : make_float4(0.f, 0.f, 0.f, 0.f);
    if (lvalid) {
        const float* __restrict__ xrow = x + (size_t)b * C_IN * L_IN + (size_t)(h*40) * L_IN + l;
        const bool has_m1 = (l >= 1);
        const bool has_p1 = (l + 1 < L_IN);
        #pragma unroll 4
        for (int c = 0; c < 40; ++c) {
            const float* r = xrow + c * L_IN;
            float xa = has_m1 ? r[-1] : 0.f;
            float xb = r[0];
            float xc = has_p1 ? r[1] : 0.f;
            float4 w0 = s_wpre[(h*40+c)*3+0], w1 = s_wpre[(h*40+c)*3+1], w2 = s_wpre[(h*40+c)*3+2];
            acc.x += w0.x*xa + w1.x*xb + w2.x*xc;
            acc.y += w0.y*xa + w1.y*xb + w2.y*xc;
            acc.z += w0.z*xa + w1.z*xb + w2.z*xc;
            acc.w += w0.w*xa + w1.w*xb + w2.w*xc;
        }
    }
    if (h == 1) s_part[i] = acc;
    __syncthreads();

    if (t < TL1 && lvalid) {
        float4 p = acc;
        float4 q2 = s_part[t];
        p.x += q2.x; p.y += q2.y; p.z += q2.z; p.w += q2.w;
        const float inv = 1.f / (p.x*p.x + p.y*p.y + p.z*p.z + p.w*p.w);
        float4 e;
        e.x = quadform(s_A[0], p) * inv;
        e.y = quadform(s_A[1], p) * inv;
        e.z = quadform(s_A[2], p) * inv;
        e.w = quadform(s_A[3], p) * inv;
        expz[(size_t)b * L_IN + l] = e;
    }
}

// ---------- K2: pure writer, fill-kernel geometry ----------
// grid (12 l-tiles, 2 o-halves, 32 b); block 256 = 4 waves.
// lane owns 4 consecutive l -> one contiguous 1KB dwordx4 segment per wave-instr.
__global__ __launch_bounds__(NT2) void expand_kernel(
    const float4* __restrict__ expz,
    const float* __restrict__ W_post,
    const float* __restrict__ b_post,
    float* __restrict__ out)
{
    __shared__ float4 s_post[OH];
    __shared__ float  s_bpost[OH];

    const int t  = threadIdx.x;
    const int b  = blockIdx.z;
    const int oh = blockIdx.y;          // o-half
    const int l0 = blockIdx.x * TL2;

    const int obase = oh * OH;
    s_post[t]  = *reinterpret_cast<const float4*>(&W_post[(obase + t) * 4]);
    s_bpost[t] = b_post[obase + t];

    const int lane = t & 63;
    const int w    = t >> 6;            // 0..3
    const int l    = l0 + 4 * lane;
    const bool v   = (l + 3 < L_IN);

    float4 e0, e1, e2, e3;
    if (v) {
        const float4* ep = expz + (size_t)b * L_IN + l;
        e0 = ep[0]; e1 = ep[1]; e2 = ep[2]; e3 = ep[3];
    }
    __syncthreads();
    if (!v) return;

    float* op = out + (size_t)b * OUT_C * L_IN + (size_t)(obase + w) * L_IN + l;
    #pragma unroll 8
    for (int k = 0; k < OH/4; ++k) {
        const int o = w + 4*k;
        const float4 wv = s_post[o];
        const float  bb = s_bpost[o];
        float4 st;
        st.x = wv.x*e0.x + wv.y*e0.y + wv.z*e0.z + wv.w*e0.w + bb;
        st.y = wv.x*e1.x + wv.y*e1.y + wv.z*e1.z + wv.w*e1.w + bb;
        st.z = wv.x*e2.x + wv.y*e2.y + wv.z*e2.z + wv.w*e2.w + bb;
        st.w = wv.x*e3.x + wv.y*e3.y + wv.z*e3.z + wv.w*e3.w + bb;
        *reinterpret_cast<float4*>(op) = st;
        op += (size_t)4 * L_IN;
    }
}

extern "C" void kernel_launch(void* const* d_in, const int* in_sizes, int n_in,
                              void* d_out, int out_size, void* d_ws, size_t ws_size,
                              hipStream_t stream) {
    const float* x      = (const float*)d_in[0];
    const float* W_pre  = (const float*)d_in[1];
    const float* b_pre  = (const float*)d_in[2];
    const float* W_post = (const float*)d_in[3];
    const float* b_post = (const float*)d_in[4];
    const float* qw     = (const float*)d_in[5];
    float* out = (float*)d_out;
    float4* expz = (float4*)d_ws;   // 32*3000*16B = 1.5 MB

    const int B = in_sizes[0] / (C_IN * L_IN);
    dim3 grid1((L_IN + TL1 - 1) / TL1, B);
    qconv_expz_kernel<<<grid1, NT1, 0, stream>>>(x, W_pre, b_pre, qw, expz);
    dim3 grid2((L_IN + TL2 - 1) / TL2, OUT_C / OH, B);
    expand_kernel<<<grid2, NT2, 0, stream>>>(expz, W_post, b_post, out);
}